// Round 10
// baseline (657.606 us; speedup 1.0000x reference)
//
#include <hip/hip_runtime.h>

typedef unsigned long long u64;
typedef unsigned int u32;
typedef unsigned short u16;

#define N_ROWS 16384
#define DIM    512
#define K_CODES 8192

#define CHUNKS 32
#define CHUNK_CODES 256
#define BMR 128              // rows per block
#define KC 32
#define KSTAGES (DIM / KC)   // 16
#define NBUF 3

typedef short bf16x8 __attribute__((ext_vector_type(8)));
typedef float f32x4  __attribute__((ext_vector_type(4)));

__device__ __forceinline__ void t2_insert(u64* a, u64 k) {
    u64 lo = a[0], hi = a[1];
    bool lt0 = k < lo;
    u64 n1k = (k < hi) ? k : hi;
    a[0] = lt0 ? k : lo;
    a[1] = lt0 ? lo : n1k;
}

// ---------------- Kernel P: precompute bf16 bit-truncation splits (verified r5) ----
__global__ void vq_split_kernel(const float* __restrict__ x, const float* __restrict__ cb,
                                u16* __restrict__ xhi, u16* __restrict__ xmid,
                                u16* __restrict__ cbhi, u16* __restrict__ cbmid) {
    size_t t = (size_t)blockIdx.x * blockDim.x + threadIdx.x;
    const size_t nx = (size_t)N_ROWS * DIM / 4;
    const size_t nc = (size_t)K_CODES * DIM / 4;
    const float4* src;
    u16 *hi, *mid;
    size_t off;
    if (t < nx)            { src = (const float4*)x;  hi = xhi;  mid = xmid;  off = t; }
    else if (t < nx + nc)  { src = (const float4*)cb; hi = cbhi; mid = cbmid; off = t - nx; }
    else return;
    float4 v = src[off];
    u32 b0 = __float_as_uint(v.x), b1 = __float_as_uint(v.y),
        b2 = __float_as_uint(v.z), b3 = __float_as_uint(v.w);
    u16 h0 = (u16)(b0 >> 16), h1 = (u16)(b1 >> 16), h2 = (u16)(b2 >> 16), h3 = (u16)(b3 >> 16);
    u16 m0 = (u16)(__float_as_uint(v.x - __uint_as_float(b0 & 0xFFFF0000u)) >> 16);
    u16 m1 = (u16)(__float_as_uint(v.y - __uint_as_float(b1 & 0xFFFF0000u)) >> 16);
    u16 m2 = (u16)(__float_as_uint(v.z - __uint_as_float(b2 & 0xFFFF0000u)) >> 16);
    u16 m3 = (u16)(__float_as_uint(v.w - __uint_as_float(b3 & 0xFFFF0000u)) >> 16);
    ((ushort4*)hi)[off]  = make_ushort4(h0, h1, h2, h3);
    ((ushort4*)mid)[off] = make_ushort4(m0, m1, m2, m3);
}

// ---------------- Kernel N: numpy-pairwise fp32 row norms (verified r3) ----------------
__device__ __forceinline__ float np_block128_sq(const float* __restrict__ q) {
    float r[8];
    #pragma unroll
    for (int j = 0; j < 8; ++j) r[j] = __fmul_rn(q[j], q[j]);
    for (int i = 8; i < 128; i += 8) {
        #pragma unroll
        for (int j = 0; j < 8; ++j) r[j] = __fadd_rn(r[j], __fmul_rn(q[i + j], q[i + j]));
    }
    return __fadd_rn(__fadd_rn(__fadd_rn(r[0], r[1]), __fadd_rn(r[2], r[3])),
                     __fadd_rn(__fadd_rn(r[4], r[5]), __fadd_rn(r[6], r[7])));
}

__global__ void vq_np_norm_kernel(const float* __restrict__ x, const float* __restrict__ cb,
                                  float* __restrict__ Arow, float* __restrict__ Bcode) {
    int t = blockIdx.x * blockDim.x + threadIdx.x;
    const float* p;
    float* o;
    if (t < N_ROWS) {
        p = x + (size_t)t * DIM;  o = Arow + t;
    } else if (t < N_ROWS + K_CODES) {
        int j = t - N_ROWS;
        p = cb + (size_t)j * DIM; o = Bcode + j;
    } else return;
    float b0 = np_block128_sq(p);
    float b1 = np_block128_sq(p + 128);
    float b2 = np_block128_sq(p + 256);
    float b3 = np_block128_sq(p + 384);
    *o = __fadd_rn(__fadd_rn(b0, b1), __fadd_rn(b2, b3));
}

// ---------------- Kernel S: MFMA screen, 128x256 block, 3-buffer depth-2 pipeline ----
// 8 waves 2M x 4N, wave tile 64x64. LDS buffer (48KB) = [AH 8K | AM 8K | BH 16K | BM 16K],
// 48 x 1KB staging segments, 6 global_load_lds per wave per stage (uniform vmcnt).
// Issue stage k+2 then s_waitcnt vmcnt(12): stage k's loads soaked ~2 stages.
// Chunk-XOR swizzle identical to r9 (measured conflict-free). MFMA per-element
// order identical to r5-r9 (kt asc x {hh,hm,mh}) -> bit-identical numerics.
__launch_bounds__(512, 2)
__global__ void vq_screen_kernel(const u16* __restrict__ xhi, const u16* __restrict__ xmid,
                                 const u16* __restrict__ cbhi, const u16* __restrict__ cbmid,
                                 const float* __restrict__ Arow,
                                 const float* __restrict__ Bcode,
                                 u64* __restrict__ top2out) {
    __shared__ __align__(16) u16 lds[NBUF][24576];   // 3 x 48KB

    const int t = threadIdx.x;
    const int lane = t & 63;
    const int w = t >> 6;        // 0..7
    const int wm = w >> 2;       // 0..1 -> rows [64*wm, +64)
    const int wn = w & 3;        // 0..3 -> cols [64*wn, +64)
    const int r15 = lane & 15;
    const int g = lane >> 4;     // 0..3
    const int cswz = (r15 >> 1) & 3;

    const int rowBase   = blockIdx.x * BMR;
    const int chunk     = blockIdx.y;
    const int chunkBase = chunk * CHUNK_CODES;

    // per-lane pre-swizzled source offset within a 16-row staging group
    const size_t laneOff = (size_t)(lane >> 2) * DIM
                         + (size_t)(((lane & 3) ^ ((lane >> 3) & 3)) * 8);

    // 6 staging segments per wave: linear q over [AH(8)|AM(8)|BH(16)|BM(16)] 1KB groups
    const u16* srcBase[6];
    int dstOff[6];
    #pragma unroll
    for (int j = 0; j < 6; ++j) {
        int q = w * 6 + j;
        const u16* gp; int grp;
        if (q < 8)       { gp = xhi   + (size_t)rowBase   * DIM; grp = q; }
        else if (q < 16) { gp = xmid  + (size_t)rowBase   * DIM; grp = q - 8; }
        else if (q < 32) { gp = cbhi  + (size_t)chunkBase * DIM; grp = q - 16; }
        else             { gp = cbmid + (size_t)chunkBase * DIM; grp = q - 32; }
        srcBase[j] = gp + (size_t)grp * 16 * DIM + laneOff;
        dstOff[j] = q * 512;   // u16 units, 1KB per segment
    }

    auto stage = [&](int kt, int b) {
        #pragma unroll
        for (int j = 0; j < 6; ++j) {
            __builtin_amdgcn_global_load_lds(
                (const __attribute__((address_space(1))) u32*)(srcBase[j] + kt * KC),
                (__attribute__((address_space(3))) u32*)(&lds[b][dstOff[j]]),
                16, 0, 0);
        }
    };

    f32x4 acc[4][4] = {};

    stage(0, 0);
    stage(1, 1);

    #pragma unroll
    for (int k = 0; k < KSTAGES; ++k) {
        if (k + 2 < KSTAGES) {
            stage(k + 2, (k + 2) % 3);
            asm volatile("s_waitcnt vmcnt(12)" ::: "memory");
        } else if (k + 1 < KSTAGES) {
            asm volatile("s_waitcnt vmcnt(6)" ::: "memory");
        } else {
            asm volatile("s_waitcnt vmcnt(0)" ::: "memory");
        }
        asm volatile("s_barrier" ::: "memory");

        u16* L = &lds[k % 3][0];
        bf16x8 Ah[4], Am[4], Bh[4], Bm[4];
        #pragma unroll
        for (int mi = 0; mi < 4; ++mi) {
            int a = (wm * 64 + mi * 16 + r15) * 32 + (g ^ cswz) * 8;
            Ah[mi] = *(const bf16x8*)&L[a];
            Am[mi] = *(const bf16x8*)&L[4096 + a];
        }
        #pragma unroll
        for (int ni = 0; ni < 4; ++ni) {
            int b = (wn * 64 + ni * 16 + r15) * 32 + (g ^ cswz) * 8;
            Bh[ni] = *(const bf16x8*)&L[8192 + b];
            Bm[ni] = *(const bf16x8*)&L[16384 + b];
        }
        __builtin_amdgcn_s_setprio(1);
        #pragma unroll
        for (int ni = 0; ni < 4; ++ni)
            #pragma unroll
            for (int mi = 0; mi < 4; ++mi) {
                acc[mi][ni] = __builtin_amdgcn_mfma_f32_16x16x32_bf16(Ah[mi], Bh[ni], acc[mi][ni], 0, 0, 0);
                acc[mi][ni] = __builtin_amdgcn_mfma_f32_16x16x32_bf16(Ah[mi], Bm[ni], acc[mi][ni], 0, 0, 0);
                acc[mi][ni] = __builtin_amdgcn_mfma_f32_16x16x32_bf16(Am[mi], Bh[ni], acc[mi][ni], 0, 0, 0);
            }
        __builtin_amdgcn_s_setprio(0);
        asm volatile("s_barrier" ::: "memory");
    }

    // ---- fold once: full-K acc -> np-fp32 dist -> per-row top-2 of this chunk ----
    u64 t2[4][4][2];
    #pragma unroll
    for (int mi = 0; mi < 4; ++mi)
        #pragma unroll
        for (int reg = 0; reg < 4; ++reg) { t2[mi][reg][0] = ~0ull; t2[mi][reg][1] = ~0ull; }

    float bjv[4];
    #pragma unroll
    for (int ni = 0; ni < 4; ++ni)
        bjv[ni] = Bcode[chunkBase + wn * 64 + ni * 16 + r15];

    #pragma unroll
    for (int mi = 0; mi < 4; ++mi) {
        float AiV[4];
        #pragma unroll
        for (int reg = 0; reg < 4; ++reg)
            AiV[reg] = Arow[rowBase + wm * 64 + mi * 16 + g * 4 + reg];
        #pragma unroll
        for (int ni = 0; ni < 4; ++ni) {
            int col = chunkBase + wn * 64 + ni * 16 + r15;
            #pragma unroll
            for (int reg = 0; reg < 4; ++reg) {
                float d = __fsub_rn(__fadd_rn(AiV[reg], bjv[ni]), 2.0f * acc[mi][ni][reg]);
                u64 key = ((u64)__float_as_uint(d) << 13) | (u64)(u32)col;
                t2_insert(t2[mi][reg], key);
            }
        }
    }

    // ---- merge across the 16 column-lanes ----
    #pragma unroll
    for (int m = 1; m <= 8; m <<= 1) {
        #pragma unroll
        for (int mi = 0; mi < 4; ++mi)
            #pragma unroll
            for (int reg = 0; reg < 4; ++reg) {
                u64 i0 = __shfl_xor(t2[mi][reg][0], m);
                u64 i1 = __shfl_xor(t2[mi][reg][1], m);
                t2_insert(t2[mi][reg], i0);
                t2_insert(t2[mi][reg], i1);
            }
    }

    // ---- merge across the 4 wn waves via LDS, write chunk top-2 ----
    __syncthreads();
    u64* t2buf = (u64*)&lds[0][0];   // [128 rows][4 wn][2 slots] = 8KB
    if (r15 == 0) {
        #pragma unroll
        for (int mi = 0; mi < 4; ++mi)
            #pragma unroll
            for (int reg = 0; reg < 4; ++reg) {
                int row = wm * 64 + mi * 16 + g * 4 + reg;
                t2buf[(row * 4 + wn) * 2 + 0] = t2[mi][reg][0];
                t2buf[(row * 4 + wn) * 2 + 1] = t2[mi][reg][1];
            }
    }
    __syncthreads();
    if (t < BMR) {
        u64 best[2];
        best[0] = t2buf[(t * 4 + 0) * 2 + 0];
        best[1] = t2buf[(t * 4 + 0) * 2 + 1];
        #pragma unroll
        for (int wq = 1; wq < 4; ++wq) {
            t2_insert(best, t2buf[(t * 4 + wq) * 2 + 0]);
            t2_insert(best, t2buf[(t * 4 + wq) * 2 + 1]);
        }
        top2out[((size_t)chunk * N_ROWS + rowBase + t) * 2 + 0] = best[0];
        top2out[((size_t)chunk * N_ROWS + rowBase + t) * 2 + 1] = best[1];
    }
}

// ---------------- Kernel R: chunk-top2 -> slice-top2 -> exact np re-decision ----------------
__global__ void vq_refine_kernel(const float* __restrict__ x, const float* __restrict__ cb,
                                 const float* __restrict__ Arow, const float* __restrict__ Bcode,
                                 const u64* __restrict__ top2, int* __restrict__ idxOut,
                                 float* __restrict__ out4) {
    int gw = (blockIdx.x * blockDim.x + threadIdx.x) >> 6;
    int lane = threadIdx.x & 63;
    if (gw >= N_ROWS) return;

    // lane <-> (chunk = lane>>1, slot = lane&1); slice s = lanes [16s,16s+16) (chunks 8s..8s+7)
    u64 key = top2[((size_t)(lane >> 1) * N_ROWS + gw) * 2 + (lane & 1)];

    u64 m1 = key;
    #pragma unroll
    for (int m = 1; m < 16; m <<= 1) { u64 o = __shfl_xor(m1, m); m1 = o < m1 ? o : m1; }
    u64 k2 = (key == m1) ? ~0ull : key;
    u64 m2 = k2;
    #pragma unroll
    for (int m = 1; m < 16; m <<= 1) { u64 o = __shfl_xor(m2, m); m2 = o < m2 ? o : m2; }

    float Ai = Arow[gw];
    const float* xr = x + (size_t)gw * DIM;
    u64 best = ~0ull;
    #pragma unroll
    for (int j = 0; j < 8; ++j) {
        u64 ck = __shfl((j & 1) ? m2 : m1, (j >> 1) * 16);
        int c = (int)(ck & 8191u);
        const float* er = cb + (size_t)c * DIM;
        double d = 0.0;
        #pragma unroll
        for (int e = 0; e < 8; ++e)
            d = fma((double)xr[e * 64 + lane], (double)er[e * 64 + lane], d);
        #pragma unroll
        for (int m = 1; m < 64; m <<= 1) d += __shfl_xor(d, m);
        float m32 = (float)d;
        float dist = __fsub_rn(__fadd_rn(Ai, Bcode[c]), 2.0f * m32);
        u64 ek = ((u64)__float_as_uint(dist) << 13) | (u64)(u32)c;
        best = ek < best ? ek : best;
    }
    if (lane == 0) {
        int c = (int)(best & 8191u);
        idxOut[gw] = c;
        out4[gw] = (float)c;
    }
}

// ---------------- Kernel C: gather + outputs + per-row loss partial ----------------
__global__ void vq_gather_kernel(const float* __restrict__ x,
                                 const float* __restrict__ cb,
                                 const int* __restrict__ idxArr,
                                 float* __restrict__ out0,
                                 float* __restrict__ out3,
                                 float* __restrict__ rowPart) {
    int gw = (blockIdx.x * blockDim.x + threadIdx.x) >> 6;
    int lane = threadIdx.x & 63;
    if (gw >= N_ROWS) return;
    int idx = idxArr[gw];
    const float2* xp = (const float2*)(x  + (size_t)gw * DIM);
    const float2* qp = (const float2*)(cb + (size_t)idx * DIM);
    float2* o0 = (float2*)(out0 + (size_t)gw * DIM);
    float2* o3 = (float2*)(out3 + (size_t)gw * DIM);
    float part = 0.0f;
    #pragma unroll
    for (int r = 0; r < 4; ++r) {
        int e = r * 64 + lane;
        float2 xv = xp[e];
        float2 qv = qp[e];
        float dx = qv.x - xv.x, dy = qv.y - xv.y;
        part += dx * dx + dy * dy;
        float2 o; o.x = xv.x + dx; o.y = xv.y + dy;
        o0[e] = o;
        o3[e] = qv;
    }
    #pragma unroll
    for (int m = 32; m; m >>= 1) part += __shfl_xor(part, m);
    if (lane == 0) rowPart[gw] = part;
}

// ---------------- Kernel D: deterministic loss reduce ----------------
__global__ void vq_loss_kernel(const float* __restrict__ rowPart,
                               float* __restrict__ out1, float* __restrict__ out2) {
    __shared__ float red[256];
    int t = threadIdx.x;
    float s = 0.0f;
    for (int r = t; r < N_ROWS; r += 256) s += rowPart[r];
    red[t] = s;
    __syncthreads();
    #pragma unroll
    for (int m = 128; m; m >>= 1) {
        if (t < m) red[t] += red[t + m];
        __syncthreads();
    }
    if (t == 0) {
        float loss = red[0] / (float)(N_ROWS * DIM);
        out1[0] = loss;
        out2[0] = loss;
    }
}

extern "C" void kernel_launch(void* const* d_in, const int* in_sizes, int n_in,
                              void* d_out, int out_size, void* d_ws, size_t ws_size,
                              hipStream_t stream) {
    const float* x  = (const float*)d_in[0];   // [16384, 512]
    const float* cb = (const float*)d_in[1];   // [8192, 512]
    float* out  = (float*)d_out;
    float* out0 = out;                         // quantized_out [8388608]
    float* out1 = out + 8388608;               // q_latent_loss [1]
    float* out2 = out + 8388609;               // e_latent_loss [1]
    float* out3 = out + 8388610;               // quantized [8388608]
    float* out4 = out + 16777218;              // idx as float [16384]

    // d_out doubles as scratch until refine/gather consume & overwrite (stream-ordered):
    // splits in [0, 12582916); chunk-top2 in the out3 tail [12582916, 14680068).
    u16* xhi   = (u16*)out0;                       // [0, 4194304) floats
    u16* xmid  = (u16*)(out + 4194304);            // [4194304, 8388608)
    u16* cbhi  = (u16*)(out + 8388612);            // [8388612, 10485764)  16B-aligned
    u16* cbmid = (u16*)(out + 10485764);           // [10485764, 12582916)
    u64* wsTop2 = (u64*)(out + 12582916);          // 32*16384*2 u64 = 8MB

    char* ws = (char*)d_ws;
    float* wsA    = (float*)ws;                    // 16384 f
    float* wsB    = (float*)(ws + 65536);          // 8192 f
    int*   wsIdx  = (int*)(ws + 98304);            // 16384 int
    float* wsPart = (float*)(ws + 163840);         // 16384 f

    hipLaunchKernelGGL(vq_split_kernel,   dim3(12288), dim3(256), 0, stream,
                       x, cb, xhi, xmid, cbhi, cbmid);
    hipLaunchKernelGGL(vq_np_norm_kernel, dim3(96), dim3(256), 0, stream, x, cb, wsA, wsB);
    hipLaunchKernelGGL(vq_screen_kernel,  dim3(N_ROWS / BMR, CHUNKS), dim3(512), 0, stream,
                       xhi, xmid, cbhi, cbmid, wsA, wsB, wsTop2);
    hipLaunchKernelGGL(vq_refine_kernel,  dim3(4096), dim3(256), 0, stream,
                       x, cb, wsA, wsB, wsTop2, wsIdx, out4);
    hipLaunchKernelGGL(vq_gather_kernel,  dim3(4096), dim3(256), 0, stream,
                       x, cb, wsIdx, out0, out3, wsPart);
    hipLaunchKernelGGL(vq_loss_kernel,    dim3(1),   dim3(256), 0, stream,
                       wsPart, out1, out2);
}

// Round 11
// 571.598 us; speedup vs baseline: 1.1505x; 1.1505x over previous
//
#include <hip/hip_runtime.h>

typedef unsigned long long u64;
typedef unsigned int u32;
typedef unsigned short u16;

#define N_ROWS 16384
#define DIM    512
#define K_CODES 8192

#define CHUNKS 32
#define CHUNK_CODES 256
#define BMR 128              // rows per block
#define KC 32
#define KSTAGES (DIM / KC)   // 16

typedef short bf16x8 __attribute__((ext_vector_type(8)));
typedef float f32x4  __attribute__((ext_vector_type(4)));

__device__ __forceinline__ void t2_insert(u64* a, u64 k) {
    u64 lo = a[0], hi = a[1];
    bool lt0 = k < lo;
    u64 n1k = (k < hi) ? k : hi;
    a[0] = lt0 ? k : lo;
    a[1] = lt0 ? lo : n1k;
}

// ---------------- Kernel P: precompute bf16 bit-truncation splits (verified r5) ----
__global__ void vq_split_kernel(const float* __restrict__ x, const float* __restrict__ cb,
                                u16* __restrict__ xhi, u16* __restrict__ xmid,
                                u16* __restrict__ cbhi, u16* __restrict__ cbmid) {
    size_t t = (size_t)blockIdx.x * blockDim.x + threadIdx.x;
    const size_t nx = (size_t)N_ROWS * DIM / 4;
    const size_t nc = (size_t)K_CODES * DIM / 4;
    const float4* src;
    u16 *hi, *mid;
    size_t off;
    if (t < nx)            { src = (const float4*)x;  hi = xhi;  mid = xmid;  off = t; }
    else if (t < nx + nc)  { src = (const float4*)cb; hi = cbhi; mid = cbmid; off = t - nx; }
    else return;
    float4 v = src[off];
    u32 b0 = __float_as_uint(v.x), b1 = __float_as_uint(v.y),
        b2 = __float_as_uint(v.z), b3 = __float_as_uint(v.w);
    u16 h0 = (u16)(b0 >> 16), h1 = (u16)(b1 >> 16), h2 = (u16)(b2 >> 16), h3 = (u16)(b3 >> 16);
    u16 m0 = (u16)(__float_as_uint(v.x - __uint_as_float(b0 & 0xFFFF0000u)) >> 16);
    u16 m1 = (u16)(__float_as_uint(v.y - __uint_as_float(b1 & 0xFFFF0000u)) >> 16);
    u16 m2 = (u16)(__float_as_uint(v.z - __uint_as_float(b2 & 0xFFFF0000u)) >> 16);
    u16 m3 = (u16)(__float_as_uint(v.w - __uint_as_float(b3 & 0xFFFF0000u)) >> 16);
    ((ushort4*)hi)[off]  = make_ushort4(h0, h1, h2, h3);
    ((ushort4*)mid)[off] = make_ushort4(m0, m1, m2, m3);
}

// ---------------- Kernel N: numpy-pairwise fp32 row norms (verified r3) ----------------
__device__ __forceinline__ float np_block128_sq(const float* __restrict__ q) {
    float r[8];
    #pragma unroll
    for (int j = 0; j < 8; ++j) r[j] = __fmul_rn(q[j], q[j]);
    for (int i = 8; i < 128; i += 8) {
        #pragma unroll
        for (int j = 0; j < 8; ++j) r[j] = __fadd_rn(r[j], __fmul_rn(q[i + j], q[i + j]));
    }
    return __fadd_rn(__fadd_rn(__fadd_rn(r[0], r[1]), __fadd_rn(r[2], r[3])),
                     __fadd_rn(__fadd_rn(r[4], r[5]), __fadd_rn(r[6], r[7])));
}

__global__ void vq_np_norm_kernel(const float* __restrict__ x, const float* __restrict__ cb,
                                  float* __restrict__ Arow, float* __restrict__ Bcode) {
    int t = blockIdx.x * blockDim.x + threadIdx.x;
    const float* p;
    float* o;
    if (t < N_ROWS) {
        p = x + (size_t)t * DIM;  o = Arow + t;
    } else if (t < N_ROWS + K_CODES) {
        int j = t - N_ROWS;
        p = cb + (size_t)j * DIM; o = Bcode + j;
    } else return;
    float b0 = np_block128_sq(p);
    float b1 = np_block128_sq(p + 128);
    float b2 = np_block128_sq(p + 256);
    float b3 = np_block128_sq(p + 384);
    *o = __fadd_rn(__fadd_rn(b0, b1), __fadd_rn(b2, b3));
}

// ---------------- Kernel S: MFMA screen, B-only LDS + A-in-registers ----------------
// 256 threads, 4 waves 2M x 2N, wave tile 64x128; block 128 rows x 256 codes.
// LDS = 2 x 32KB (B planes only) -> 2 blocks/CU for cross-block phase overlap.
// A fragments load global->reg (lane's 16B IS its MFMA operand). Depth-1 prefetch,
// counted vmcnt(16) = 8 B-staging lds-loads + 8 A-reg loads in flight.
// Chunk-XOR swizzle on B both sides (verified r9). MFMA per-element order
// identical to r5-r10 (kt asc x {hh,hm,mh}) -> bit-identical scores.
__launch_bounds__(256, 2)
__global__ void vq_screen_kernel(const u16* __restrict__ xhi, const u16* __restrict__ xmid,
                                 const u16* __restrict__ cbhi, const u16* __restrict__ cbmid,
                                 const float* __restrict__ Arow,
                                 const float* __restrict__ Bcode,
                                 u64* __restrict__ top2out) {
    __shared__ __align__(16) u16 lds[2][16384];   // 2 x 32KB: BH [256][32] | BM [256][32]

    const int t = threadIdx.x;
    const int lane = t & 63;
    const int w = t >> 6;        // 0..3
    const int wm = w >> 1;       // 0..1 -> rows [64*wm, +64)
    const int wn = w & 1;        // 0..1 -> cols [128*wn, +128)
    const int r15 = lane & 15;
    const int g = lane >> 4;     // 0..3
    const int cswz = (r15 >> 1) & 3;

    const int rowBase   = blockIdx.x * BMR;
    const int chunkBase = blockIdx.y * CHUNK_CODES;

    // ---- B staging: wave w stages plane (w<2 ? BH : BM), code half (w&1) ----
    const size_t laneOff = (size_t)(lane >> 2) * DIM
                         + (size_t)(((lane & 3) ^ ((lane >> 3) & 3)) * 8);
    const u16* gpw = ((w < 2) ? cbhi : cbmid)
                   + (size_t)(chunkBase + (w & 1) * 128) * DIM + laneOff;
    const int dstW = w * 4096;   // u16 units: (w*8 segments) * 512

    auto stage = [&](int kt, int b) {
        #pragma unroll
        for (int j = 0; j < 8; ++j) {
            __builtin_amdgcn_global_load_lds(
                (const __attribute__((address_space(1))) u32*)(gpw + (size_t)j * 16 * DIM + kt * KC),
                (__attribute__((address_space(3))) u32*)(&lds[b][dstW + j * 512]),
                16, 0, 0);
        }
    };

    // ---- A direct-to-register loads ----
    const int rowA = rowBase + wm * 64 + r15;
    const u16* aH = xhi  + (size_t)rowA * DIM + g * 8;
    const u16* aM = xmid + (size_t)rowA * DIM + g * 8;

    bf16x8 A0[2][4], A1[2][4];
    auto loadA = [&](int kt, bf16x8 (&An)[2][4]) {
        #pragma unroll
        for (int mi = 0; mi < 4; ++mi) {
            size_t o = (size_t)mi * 16 * DIM + kt * KC;
            An[0][mi] = *(const bf16x8*)(aH + o);
            An[1][mi] = *(const bf16x8*)(aM + o);
        }
    };

    f32x4 acc[4][8] = {};

    auto compute = [&](const u16* L, bf16x8 (&An)[2][4]) {
        __builtin_amdgcn_s_setprio(1);
        #pragma unroll
        for (int ni = 0; ni < 8; ++ni) {
            int b = (wn * 128 + ni * 16 + r15) * 32 + (g ^ cswz) * 8;
            bf16x8 Bh = *(const bf16x8*)&L[b];
            bf16x8 Bm = *(const bf16x8*)&L[8192 + b];
            #pragma unroll
            for (int mi = 0; mi < 4; ++mi) {
                acc[mi][ni] = __builtin_amdgcn_mfma_f32_16x16x32_bf16(An[0][mi], Bh, acc[mi][ni], 0, 0, 0);
                acc[mi][ni] = __builtin_amdgcn_mfma_f32_16x16x32_bf16(An[0][mi], Bm, acc[mi][ni], 0, 0, 0);
                acc[mi][ni] = __builtin_amdgcn_mfma_f32_16x16x32_bf16(An[1][mi], Bh, acc[mi][ni], 0, 0, 0);
            }
        }
        __builtin_amdgcn_s_setprio(0);
    };

    stage(0, 0);
    loadA(0, A0);

    #pragma unroll
    for (int kk = 0; kk < KSTAGES; kk += 2) {
        // even stage kk: buf 0, A0
        if (kk + 1 < KSTAGES) {
            stage(kk + 1, 1);
            loadA(kk + 1, A1);
            asm volatile("s_waitcnt vmcnt(16)" ::: "memory");
        } else {
            asm volatile("s_waitcnt vmcnt(0)" ::: "memory");
        }
        asm volatile("s_barrier" ::: "memory");
        compute(&lds[0][0], A0);
        asm volatile("s_barrier" ::: "memory");

        // odd stage kk+1: buf 1, A1
        if (kk + 2 < KSTAGES) {
            stage(kk + 2, 0);
            loadA(kk + 2, A0);
            asm volatile("s_waitcnt vmcnt(16)" ::: "memory");
        } else {
            asm volatile("s_waitcnt vmcnt(0)" ::: "memory");
        }
        asm volatile("s_barrier" ::: "memory");
        compute(&lds[1][0], A1);
        asm volatile("s_barrier" ::: "memory");
    }

    // ---- fold once: full-K acc -> np-fp32 dist -> per-row top-2 of this chunk ----
    u64 t2[4][4][2];
    #pragma unroll
    for (int mi = 0; mi < 4; ++mi)
        #pragma unroll
        for (int reg = 0; reg < 4; ++reg) { t2[mi][reg][0] = ~0ull; t2[mi][reg][1] = ~0ull; }

    float bjv[8];
    #pragma unroll
    for (int ni = 0; ni < 8; ++ni)
        bjv[ni] = Bcode[chunkBase + wn * 128 + ni * 16 + r15];

    #pragma unroll
    for (int mi = 0; mi < 4; ++mi) {
        float AiV[4];
        #pragma unroll
        for (int reg = 0; reg < 4; ++reg)
            AiV[reg] = Arow[rowBase + wm * 64 + mi * 16 + g * 4 + reg];
        #pragma unroll
        for (int ni = 0; ni < 8; ++ni) {
            int col = chunkBase + wn * 128 + ni * 16 + r15;
            #pragma unroll
            for (int reg = 0; reg < 4; ++reg) {
                float d = __fsub_rn(__fadd_rn(AiV[reg], bjv[ni]), 2.0f * acc[mi][ni][reg]);
                u64 key = ((u64)__float_as_uint(d) << 13) | (u64)(u32)col;
                t2_insert(t2[mi][reg], key);
            }
        }
    }

    // ---- merge across the 16 column-lanes ----
    #pragma unroll
    for (int m = 1; m <= 8; m <<= 1) {
        #pragma unroll
        for (int mi = 0; mi < 4; ++mi)
            #pragma unroll
            for (int reg = 0; reg < 4; ++reg) {
                u64 i0 = __shfl_xor(t2[mi][reg][0], m);
                u64 i1 = __shfl_xor(t2[mi][reg][1], m);
                t2_insert(t2[mi][reg], i0);
                t2_insert(t2[mi][reg], i1);
            }
    }

    // ---- merge across the 2 wn waves via LDS, write chunk top-2 ----
    __syncthreads();
    u64* t2buf = (u64*)&lds[0][0];   // [128 rows][2 wn][2 slots] = 4KB
    if (r15 == 0) {
        #pragma unroll
        for (int mi = 0; mi < 4; ++mi)
            #pragma unroll
            for (int reg = 0; reg < 4; ++reg) {
                int row = wm * 64 + mi * 16 + g * 4 + reg;
                t2buf[(row * 2 + wn) * 2 + 0] = t2[mi][reg][0];
                t2buf[(row * 2 + wn) * 2 + 1] = t2[mi][reg][1];
            }
    }
    __syncthreads();
    if (t < BMR) {
        u64 best[2];
        best[0] = t2buf[(t * 2 + 0) * 2 + 0];
        best[1] = t2buf[(t * 2 + 0) * 2 + 1];
        t2_insert(best, t2buf[(t * 2 + 1) * 2 + 0]);
        t2_insert(best, t2buf[(t * 2 + 1) * 2 + 1]);
        top2out[((size_t)blockIdx.y * N_ROWS + rowBase + t) * 2 + 0] = best[0];
        top2out[((size_t)blockIdx.y * N_ROWS + rowBase + t) * 2 + 1] = best[1];
    }
}

// ---------------- Kernel R: chunk-top2 -> slice-top2 -> exact np re-decision ----------------
__global__ void vq_refine_kernel(const float* __restrict__ x, const float* __restrict__ cb,
                                 const float* __restrict__ Arow, const float* __restrict__ Bcode,
                                 const u64* __restrict__ top2, int* __restrict__ idxOut,
                                 float* __restrict__ out4) {
    int gw = (blockIdx.x * blockDim.x + threadIdx.x) >> 6;
    int lane = threadIdx.x & 63;
    if (gw >= N_ROWS) return;

    // lane <-> (chunk = lane>>1, slot = lane&1); slice s = lanes [16s,16s+16) (chunks 8s..8s+7)
    u64 key = top2[((size_t)(lane >> 1) * N_ROWS + gw) * 2 + (lane & 1)];

    u64 m1 = key;
    #pragma unroll
    for (int m = 1; m < 16; m <<= 1) { u64 o = __shfl_xor(m1, m); m1 = o < m1 ? o : m1; }
    u64 k2 = (key == m1) ? ~0ull : key;
    u64 m2 = k2;
    #pragma unroll
    for (int m = 1; m < 16; m <<= 1) { u64 o = __shfl_xor(m2, m); m2 = o < m2 ? o : m2; }

    float Ai = Arow[gw];
    const float* xr = x + (size_t)gw * DIM;
    u64 best = ~0ull;
    #pragma unroll
    for (int j = 0; j < 8; ++j) {
        u64 ck = __shfl((j & 1) ? m2 : m1, (j >> 1) * 16);
        int c = (int)(ck & 8191u);
        const float* er = cb + (size_t)c * DIM;
        double d = 0.0;
        #pragma unroll
        for (int e = 0; e < 8; ++e)
            d = fma((double)xr[e * 64 + lane], (double)er[e * 64 + lane], d);
        #pragma unroll
        for (int m = 1; m < 64; m <<= 1) d += __shfl_xor(d, m);
        float m32 = (float)d;
        float dist = __fsub_rn(__fadd_rn(Ai, Bcode[c]), 2.0f * m32);
        u64 ek = ((u64)__float_as_uint(dist) << 13) | (u64)(u32)c;
        best = ek < best ? ek : best;
    }
    if (lane == 0) {
        int c = (int)(best & 8191u);
        idxOut[gw] = c;
        out4[gw] = (float)c;
    }
}

// ---------------- Kernel C: gather + outputs + per-row loss partial ----------------
__global__ void vq_gather_kernel(const float* __restrict__ x,
                                 const float* __restrict__ cb,
                                 const int* __restrict__ idxArr,
                                 float* __restrict__ out0,
                                 float* __restrict__ out3,
                                 float* __restrict__ rowPart) {
    int gw = (blockIdx.x * blockDim.x + threadIdx.x) >> 6;
    int lane = threadIdx.x & 63;
    if (gw >= N_ROWS) return;
    int idx = idxArr[gw];
    const float2* xp = (const float2*)(x  + (size_t)gw * DIM);
    const float2* qp = (const float2*)(cb + (size_t)idx * DIM);
    float2* o0 = (float2*)(out0 + (size_t)gw * DIM);
    float2* o3 = (float2*)(out3 + (size_t)gw * DIM);
    float part = 0.0f;
    #pragma unroll
    for (int r = 0; r < 4; ++r) {
        int e = r * 64 + lane;
        float2 xv = xp[e];
        float2 qv = qp[e];
        float dx = qv.x - xv.x, dy = qv.y - xv.y;
        part += dx * dx + dy * dy;
        float2 o; o.x = xv.x + dx; o.y = xv.y + dy;
        o0[e] = o;
        o3[e] = qv;
    }
    #pragma unroll
    for (int m = 32; m; m >>= 1) part += __shfl_xor(part, m);
    if (lane == 0) rowPart[gw] = part;
}

// ---------------- Kernel D: deterministic loss reduce ----------------
__global__ void vq_loss_kernel(const float* __restrict__ rowPart,
                               float* __restrict__ out1, float* __restrict__ out2) {
    __shared__ float red[256];
    int t = threadIdx.x;
    float s = 0.0f;
    for (int r = t; r < N_ROWS; r += 256) s += rowPart[r];
    red[t] = s;
    __syncthreads();
    #pragma unroll
    for (int m = 128; m; m >>= 1) {
        if (t < m) red[t] += red[t + m];
        __syncthreads();
    }
    if (t == 0) {
        float loss = red[0] / (float)(N_ROWS * DIM);
        out1[0] = loss;
        out2[0] = loss;
    }
}

extern "C" void kernel_launch(void* const* d_in, const int* in_sizes, int n_in,
                              void* d_out, int out_size, void* d_ws, size_t ws_size,
                              hipStream_t stream) {
    const float* x  = (const float*)d_in[0];   // [16384, 512]
    const float* cb = (const float*)d_in[1];   // [8192, 512]
    float* out  = (float*)d_out;
    float* out0 = out;                         // quantized_out [8388608]
    float* out1 = out + 8388608;               // q_latent_loss [1]
    float* out2 = out + 8388609;               // e_latent_loss [1]
    float* out3 = out + 8388610;               // quantized [8388608]
    float* out4 = out + 16777218;              // idx as float [16384]

    // d_out doubles as scratch until refine/gather consume & overwrite (stream-ordered):
    // splits in [0, 12582916); chunk-top2 in the out3 tail [12582916, 14680068).
    u16* xhi   = (u16*)out0;                       // [0, 4194304) floats
    u16* xmid  = (u16*)(out + 4194304);            // [4194304, 8388608)
    u16* cbhi  = (u16*)(out + 8388612);            // [8388612, 10485764)  16B-aligned
    u16* cbmid = (u16*)(out + 10485764);           // [10485764, 12582916)
    u64* wsTop2 = (u64*)(out + 12582916);          // 32*16384*2 u64 = 8MB

    char* ws = (char*)d_ws;
    float* wsA    = (float*)ws;                    // 16384 f
    float* wsB    = (float*)(ws + 65536);          // 8192 f
    int*   wsIdx  = (int*)(ws + 98304);            // 16384 int
    float* wsPart = (float*)(ws + 163840);         // 16384 f

    hipLaunchKernelGGL(vq_split_kernel,   dim3(12288), dim3(256), 0, stream,
                       x, cb, xhi, xmid, cbhi, cbmid);
    hipLaunchKernelGGL(vq_np_norm_kernel, dim3(96), dim3(256), 0, stream, x, cb, wsA, wsB);
    hipLaunchKernelGGL(vq_screen_kernel,  dim3(N_ROWS / BMR, CHUNKS), dim3(256), 0, stream,
                       xhi, xmid, cbhi, cbmid, wsA, wsB, wsTop2);
    hipLaunchKernelGGL(vq_refine_kernel,  dim3(4096), dim3(256), 0, stream,
                       x, cb, wsA, wsB, wsTop2, wsIdx, out4);
    hipLaunchKernelGGL(vq_gather_kernel,  dim3(4096), dim3(256), 0, stream,
                       x, cb, wsIdx, out0, out3, wsPart);
    hipLaunchKernelGGL(vq_loss_kernel,    dim3(1),   dim3(256), 0, stream,
                       wsPart, out1, out2);
}

// Round 12
// 550.196 us; speedup vs baseline: 1.1952x; 1.0389x over previous
//
#include <hip/hip_runtime.h>

typedef unsigned long long u64;
typedef unsigned int u32;
typedef unsigned short u16;

#define N_ROWS 16384
#define DIM    512
#define K_CODES 8192

#define CHUNKS 32
#define CHUNK_CODES 256
#define BMS 256
#define KC 32
#define KTILES (DIM / KC)    // 16

typedef short bf16x8 __attribute__((ext_vector_type(8)));
typedef float f32x4  __attribute__((ext_vector_type(4)));

// plane offsets in u16 units within one 64KB buffer
#define P_AH 0
#define P_AM 8192
#define P_BH 16384
#define P_BM 24576

__device__ __forceinline__ void t2_insert(u64* a, u64 k) {
    u64 lo = a[0], hi = a[1];
    bool lt0 = k < lo;
    u64 n1k = (k < hi) ? k : hi;
    a[0] = lt0 ? k : lo;
    a[1] = lt0 ? lo : n1k;
}

// ---------------- Kernel P: precompute bf16 bit-truncation splits (verified r5) ----
__global__ void vq_split_kernel(const float* __restrict__ x, const float* __restrict__ cb,
                                u16* __restrict__ xhi, u16* __restrict__ xmid,
                                u16* __restrict__ cbhi, u16* __restrict__ cbmid) {
    size_t t = (size_t)blockIdx.x * blockDim.x + threadIdx.x;
    const size_t nx = (size_t)N_ROWS * DIM / 4;
    const size_t nc = (size_t)K_CODES * DIM / 4;
    const float4* src;
    u16 *hi, *mid;
    size_t off;
    if (t < nx)            { src = (const float4*)x;  hi = xhi;  mid = xmid;  off = t; }
    else if (t < nx + nc)  { src = (const float4*)cb; hi = cbhi; mid = cbmid; off = t - nx; }
    else return;
    float4 v = src[off];
    u32 b0 = __float_as_uint(v.x), b1 = __float_as_uint(v.y),
        b2 = __float_as_uint(v.z), b3 = __float_as_uint(v.w);
    u16 h0 = (u16)(b0 >> 16), h1 = (u16)(b1 >> 16), h2 = (u16)(b2 >> 16), h3 = (u16)(b3 >> 16);
    u16 m0 = (u16)(__float_as_uint(v.x - __uint_as_float(b0 & 0xFFFF0000u)) >> 16);
    u16 m1 = (u16)(__float_as_uint(v.y - __uint_as_float(b1 & 0xFFFF0000u)) >> 16);
    u16 m2 = (u16)(__float_as_uint(v.z - __uint_as_float(b2 & 0xFFFF0000u)) >> 16);
    u16 m3 = (u16)(__float_as_uint(v.w - __uint_as_float(b3 & 0xFFFF0000u)) >> 16);
    ((ushort4*)hi)[off]  = make_ushort4(h0, h1, h2, h3);
    ((ushort4*)mid)[off] = make_ushort4(m0, m1, m2, m3);
}

// ---------------- Kernel N: numpy-pairwise fp32 row norms (verified r3) ----------------
__device__ __forceinline__ float np_block128_sq(const float* __restrict__ q) {
    float r[8];
    #pragma unroll
    for (int j = 0; j < 8; ++j) r[j] = __fmul_rn(q[j], q[j]);
    for (int i = 8; i < 128; i += 8) {
        #pragma unroll
        for (int j = 0; j < 8; ++j) r[j] = __fadd_rn(r[j], __fmul_rn(q[i + j], q[i + j]));
    }
    return __fadd_rn(__fadd_rn(__fadd_rn(r[0], r[1]), __fadd_rn(r[2], r[3])),
                     __fadd_rn(__fadd_rn(r[4], r[5]), __fadd_rn(r[6], r[7])));
}

__global__ void vq_np_norm_kernel(const float* __restrict__ x, const float* __restrict__ cb,
                                  float* __restrict__ Arow, float* __restrict__ Bcode) {
    int t = blockIdx.x * blockDim.x + threadIdx.x;
    const float* p;
    float* o;
    if (t < N_ROWS) {
        p = x + (size_t)t * DIM;  o = Arow + t;
    } else if (t < N_ROWS + K_CODES) {
        int j = t - N_ROWS;
        p = cb + (size_t)j * DIM; o = Bcode + j;
    } else return;
    float b0 = np_block128_sq(p);
    float b1 = np_block128_sq(p + 128);
    float b2 = np_block128_sq(p + 256);
    float b3 = np_block128_sq(p + 384);
    *o = __fadd_rn(__fadd_rn(b0, b1), __fadd_rn(b2, b3));
}

// ---------------- Kernel S: 3-phase-per-K-tile MFMA screen (m201-style schedule) ----
// 256x256 block, 8 waves (2M x 4N), wave tile 128x64 (8mi x 4ni).
// LDS 2 x 64KB = dbuf x [Ah|Am|Bh|Bm], each plane [256][32] bf16.
// Per K-tile t (buffers alternate): 3 phases; each phase issues one-or-two plane
// stages for tile t+1 (other buffer), waits counted vmcnt(8) (drains exactly the
// plane(s) this phase reads), one barrier, ds_reads, 32 independent MFMAs.
// Per-acc-element order: kt asc x {hh, hm, mh} == r5-r11 -> bit-identical scores.
__launch_bounds__(512, 2)
__global__ void vq_screen_kernel(const u16* __restrict__ xhi, const u16* __restrict__ xmid,
                                 const u16* __restrict__ cbhi, const u16* __restrict__ cbmid,
                                 const float* __restrict__ Arow,
                                 const float* __restrict__ Bcode,
                                 u64* __restrict__ top2out) {
    __shared__ __align__(16) u16 lds[2 * 32768];   // 2 x 64KB

    const int t = threadIdx.x;
    const int lane = t & 63;
    const int w = t >> 6;        // 0..7
    const int wm = w >> 2;       // 0..1 -> rows [128*wm, +128)
    const int wn = w & 3;        // 0..3 -> cols [64*wn, +64)
    const int r15 = lane & 15;
    const int g = lane >> 4;     // 0..3
    const int cswz = (r15 >> 1) & 3;

    const int rowBase   = blockIdx.x * BMS;
    const int chunkBase = blockIdx.y * CHUNK_CODES;

    // per-lane pre-swizzled source offset (verified r9: conflict-free with read side)
    const size_t laneOff = (size_t)(lane >> 2) * DIM
                         + (size_t)(((lane & 3) ^ ((lane >> 3) & 3)) * 8);

    const u16* gA_h = xhi   + (size_t)rowBase   * DIM + laneOff;
    const u16* gA_m = xmid  + (size_t)rowBase   * DIM + laneOff;
    const u16* gB_h = cbhi  + (size_t)chunkBase * DIM + laneOff;
    const u16* gB_m = cbmid + (size_t)chunkBase * DIM + laneOff;

    // stage one plane (16KB = 2 wave-instrs) of tile kt into buffer b
    auto stageP = [&](const u16* gp, int pOff, int kt, int b) {
        #pragma unroll
        for (int j = 0; j < 2; ++j) {
            int grp = j * 8 + w;   // 16-row group, wave-uniform
            __builtin_amdgcn_global_load_lds(
                (const __attribute__((address_space(1))) u32*)(gp + (size_t)grp * 16 * DIM + kt * KC),
                (__attribute__((address_space(3))) u32*)(&lds[b * 32768 + pOff + grp * 512]),
                16, 0, 0);
        }
    };

    f32x4 acc[8][4] = {};

    // prologue: tile 0, issue order Ah,Bh,Bm,Am (drain accounting depends on it)
    stageP(gA_h, P_AH, 0, 0);
    stageP(gB_h, P_BH, 0, 0);
    stageP(gB_m, P_BM, 0, 0);
    stageP(gA_m, P_AM, 0, 0);

    #pragma unroll
    for (int kt = 0; kt < KTILES; ++kt) {
        const int bc = kt & 1, bn = bc ^ 1;
        const u16* L = &lds[bc * 32768];
        const bool pre = (kt + 1 < KTILES);

        bf16x8 Ah[8], Bh[4], Bm[4];

        // ---- phase 0: hh ----
        if (pre) { stageP(gA_h, P_AH, kt + 1, bn); stageP(gB_h, P_BH, kt + 1, bn); }
        if (pre) asm volatile("s_waitcnt vmcnt(8)" ::: "memory");
        else     asm volatile("s_waitcnt vmcnt(4)" ::: "memory");
        asm volatile("s_barrier" ::: "memory");
        #pragma unroll
        for (int mi = 0; mi < 8; ++mi)
            Ah[mi] = *(const bf16x8*)&L[P_AH + (wm * 128 + mi * 16 + r15) * 32 + (g ^ cswz) * 8];
        #pragma unroll
        for (int ni = 0; ni < 4; ++ni)
            Bh[ni] = *(const bf16x8*)&L[P_BH + (wn * 64 + ni * 16 + r15) * 32 + (g ^ cswz) * 8];
        __builtin_amdgcn_s_setprio(1);
        #pragma unroll
        for (int ni = 0; ni < 4; ++ni)
            #pragma unroll
            for (int mi = 0; mi < 8; ++mi)
                acc[mi][ni] = __builtin_amdgcn_mfma_f32_16x16x32_bf16(Ah[mi], Bh[ni], acc[mi][ni], 0, 0, 0);
        __builtin_amdgcn_s_setprio(0);

        // ---- phase 1: hm ----
        if (pre) stageP(gB_m, P_BM, kt + 1, bn);
        if (pre) asm volatile("s_waitcnt vmcnt(8)" ::: "memory");
        else     asm volatile("s_waitcnt vmcnt(2)" ::: "memory");
        asm volatile("s_barrier" ::: "memory");
        #pragma unroll
        for (int ni = 0; ni < 4; ++ni)
            Bm[ni] = *(const bf16x8*)&L[P_BM + (wn * 64 + ni * 16 + r15) * 32 + (g ^ cswz) * 8];
        __builtin_amdgcn_s_setprio(1);
        #pragma unroll
        for (int ni = 0; ni < 4; ++ni)
            #pragma unroll
            for (int mi = 0; mi < 8; ++mi)
                acc[mi][ni] = __builtin_amdgcn_mfma_f32_16x16x32_bf16(Ah[mi], Bm[ni], acc[mi][ni], 0, 0, 0);
        __builtin_amdgcn_s_setprio(0);

        // ---- phase 2: mh ----
        if (pre) stageP(gA_m, P_AM, kt + 1, bn);
        if (pre) asm volatile("s_waitcnt vmcnt(8)" ::: "memory");
        else     asm volatile("s_waitcnt vmcnt(0)" ::: "memory");
        asm volatile("s_barrier" ::: "memory");
        {
            bf16x8 Am[8];
            #pragma unroll
            for (int mi = 0; mi < 8; ++mi)
                Am[mi] = *(const bf16x8*)&L[P_AM + (wm * 128 + mi * 16 + r15) * 32 + (g ^ cswz) * 8];
            __builtin_amdgcn_s_setprio(1);
            #pragma unroll
            for (int ni = 0; ni < 4; ++ni)
                #pragma unroll
                for (int mi = 0; mi < 8; ++mi)
                    acc[mi][ni] = __builtin_amdgcn_mfma_f32_16x16x32_bf16(Am[mi], Bh[ni], acc[mi][ni], 0, 0, 0);
            __builtin_amdgcn_s_setprio(0);
        }
        asm volatile("s_barrier" ::: "memory");
    }

    // ---- fold: per-mi to keep register peak low ----
    __syncthreads();
    u64* t2buf = (u64*)&lds[0];   // [256 rows][4 wn][2 slots] = 16KB

    float bjv[4];
    #pragma unroll
    for (int ni = 0; ni < 4; ++ni)
        bjv[ni] = Bcode[chunkBase + wn * 64 + ni * 16 + r15];

    #pragma unroll
    for (int mi = 0; mi < 8; ++mi) {
        float AiV[4];
        #pragma unroll
        for (int reg = 0; reg < 4; ++reg)
            AiV[reg] = Arow[rowBase + wm * 128 + mi * 16 + g * 4 + reg];
        u64 t2r[4][2];
        #pragma unroll
        for (int reg = 0; reg < 4; ++reg) { t2r[reg][0] = ~0ull; t2r[reg][1] = ~0ull; }
        #pragma unroll
        for (int ni = 0; ni < 4; ++ni) {
            int col = chunkBase + wn * 64 + ni * 16 + r15;
            #pragma unroll
            for (int reg = 0; reg < 4; ++reg) {
                float d = __fsub_rn(__fadd_rn(AiV[reg], bjv[ni]), 2.0f * acc[mi][ni][reg]);
                u64 key = ((u64)__float_as_uint(d) << 13) | (u64)(u32)col;
                t2_insert(t2r[reg], key);
            }
        }
        #pragma unroll
        for (int m = 1; m <= 8; m <<= 1) {
            #pragma unroll
            for (int reg = 0; reg < 4; ++reg) {
                u64 i0 = __shfl_xor(t2r[reg][0], m);
                u64 i1 = __shfl_xor(t2r[reg][1], m);
                t2_insert(t2r[reg], i0);
                t2_insert(t2r[reg], i1);
            }
        }
        if (r15 == 0) {
            #pragma unroll
            for (int reg = 0; reg < 4; ++reg) {
                int row = wm * 128 + mi * 16 + g * 4 + reg;
                t2buf[(row * 4 + wn) * 2 + 0] = t2r[reg][0];
                t2buf[(row * 4 + wn) * 2 + 1] = t2r[reg][1];
            }
        }
    }
    __syncthreads();
    if (t < BMS) {
        u64 best[2];
        best[0] = t2buf[(t * 4 + 0) * 2 + 0];
        best[1] = t2buf[(t * 4 + 0) * 2 + 1];
        #pragma unroll
        for (int wq = 1; wq < 4; ++wq) {
            t2_insert(best, t2buf[(t * 4 + wq) * 2 + 0]);
            t2_insert(best, t2buf[(t * 4 + wq) * 2 + 1]);
        }
        top2out[((size_t)blockIdx.y * N_ROWS + rowBase + t) * 2 + 0] = best[0];
        top2out[((size_t)blockIdx.y * N_ROWS + rowBase + t) * 2 + 1] = best[1];
    }
}

// ---------------- Kernel R: chunk-top2 -> exact np re-decision (verified r8-r11) ----
__global__ void vq_refine_kernel(const float* __restrict__ x, const float* __restrict__ cb,
                                 const float* __restrict__ Arow, const float* __restrict__ Bcode,
                                 const u64* __restrict__ top2, int* __restrict__ idxOut,
                                 float* __restrict__ out4) {
    int gw = (blockIdx.x * blockDim.x + threadIdx.x) >> 6;
    int lane = threadIdx.x & 63;
    if (gw >= N_ROWS) return;

    u64 key = top2[((size_t)(lane >> 1) * N_ROWS + gw) * 2 + (lane & 1)];

    u64 m1 = key;
    #pragma unroll
    for (int m = 1; m < 16; m <<= 1) { u64 o = __shfl_xor(m1, m); m1 = o < m1 ? o : m1; }
    u64 k2 = (key == m1) ? ~0ull : key;
    u64 m2 = k2;
    #pragma unroll
    for (int m = 1; m < 16; m <<= 1) { u64 o = __shfl_xor(m2, m); m2 = o < m2 ? o : m2; }

    float Ai = Arow[gw];
    const float* xr = x + (size_t)gw * DIM;
    u64 best = ~0ull;
    #pragma unroll
    for (int j = 0; j < 8; ++j) {
        u64 ck = __shfl((j & 1) ? m2 : m1, (j >> 1) * 16);
        int c = (int)(ck & 8191u);
        const float* er = cb + (size_t)c * DIM;
        double d = 0.0;
        #pragma unroll
        for (int e = 0; e < 8; ++e)
            d = fma((double)xr[e * 64 + lane], (double)er[e * 64 + lane], d);
        #pragma unroll
        for (int m = 1; m < 64; m <<= 1) d += __shfl_xor(d, m);
        float m32 = (float)d;
        float dist = __fsub_rn(__fadd_rn(Ai, Bcode[c]), 2.0f * m32);
        u64 ek = ((u64)__float_as_uint(dist) << 13) | (u64)(u32)c;
        best = ek < best ? ek : best;
    }
    if (lane == 0) {
        int c = (int)(best & 8191u);
        idxOut[gw] = c;
        out4[gw] = (float)c;
    }
}

// ---------------- Kernel C: gather + outputs + per-row loss partial ----------------
__global__ void vq_gather_kernel(const float* __restrict__ x,
                                 const float* __restrict__ cb,
                                 const int* __restrict__ idxArr,
                                 float* __restrict__ out0,
                                 float* __restrict__ out3,
                                 float* __restrict__ rowPart) {
    int gw = (blockIdx.x * blockDim.x + threadIdx.x) >> 6;
    int lane = threadIdx.x & 63;
    if (gw >= N_ROWS) return;
    int idx = idxArr[gw];
    const float2* xp = (const float2*)(x  + (size_t)gw * DIM);
    const float2* qp = (const float2*)(cb + (size_t)idx * DIM);
    float2* o0 = (float2*)(out0 + (size_t)gw * DIM);
    float2* o3 = (float2*)(out3 + (size_t)gw * DIM);
    float part = 0.0f;
    #pragma unroll
    for (int r = 0; r < 4; ++r) {
        int e = r * 64 + lane;
        float2 xv = xp[e];
        float2 qv = qp[e];
        float dx = qv.x - xv.x, dy = qv.y - xv.y;
        part += dx * dx + dy * dy;
        float2 o; o.x = xv.x + dx; o.y = xv.y + dy;
        o0[e] = o;
        o3[e] = qv;
    }
    #pragma unroll
    for (int m = 32; m; m >>= 1) part += __shfl_xor(part, m);
    if (lane == 0) rowPart[gw] = part;
}

// ---------------- Kernel D: deterministic loss reduce ----------------
__global__ void vq_loss_kernel(const float* __restrict__ rowPart,
                               float* __restrict__ out1, float* __restrict__ out2) {
    __shared__ float red[256];
    int t = threadIdx.x;
    float s = 0.0f;
    for (int r = t; r < N_ROWS; r += 256) s += rowPart[r];
    red[t] = s;
    __syncthreads();
    #pragma unroll
    for (int m = 128; m; m >>= 1) {
        if (t < m) red[t] += red[t + m];
        __syncthreads();
    }
    if (t == 0) {
        float loss = red[0] / (float)(N_ROWS * DIM);
        out1[0] = loss;
        out2[0] = loss;
    }
}

extern "C" void kernel_launch(void* const* d_in, const int* in_sizes, int n_in,
                              void* d_out, int out_size, void* d_ws, size_t ws_size,
                              hipStream_t stream) {
    const float* x  = (const float*)d_in[0];   // [16384, 512]
    const float* cb = (const float*)d_in[1];   // [8192, 512]
    float* out  = (float*)d_out;
    float* out0 = out;                         // quantized_out [8388608]
    float* out1 = out + 8388608;               // q_latent_loss [1]
    float* out2 = out + 8388609;               // e_latent_loss [1]
    float* out3 = out + 8388610;               // quantized [8388608]
    float* out4 = out + 16777218;              // idx as float [16384]

    // d_out doubles as scratch until refine/gather consume & overwrite (stream-ordered):
    // splits in [0, 12582916); chunk-top2 in the out3 tail [12582916, 14680068).
    u16* xhi   = (u16*)out0;                       // [0, 4194304) floats
    u16* xmid  = (u16*)(out + 4194304);            // [4194304, 8388608)
    u16* cbhi  = (u16*)(out + 8388612);            // [8388612, 10485764)  16B-aligned
    u16* cbmid = (u16*)(out + 10485764);           // [10485764, 12582916)
    u64* wsTop2 = (u64*)(out + 12582916);          // 32*16384*2 u64 = 8MB

    char* ws = (char*)d_ws;
    float* wsA    = (float*)ws;                    // 16384 f
    float* wsB    = (float*)(ws + 65536);          // 8192 f
    int*   wsIdx  = (int*)(ws + 98304);            // 16384 int
    float* wsPart = (float*)(ws + 163840);         // 16384 f

    hipLaunchKernelGGL(vq_split_kernel,   dim3(12288), dim3(256), 0, stream,
                       x, cb, xhi, xmid, cbhi, cbmid);
    hipLaunchKernelGGL(vq_np_norm_kernel, dim3(96), dim3(256), 0, stream, x, cb, wsA, wsB);
    hipLaunchKernelGGL(vq_screen_kernel,  dim3(N_ROWS / BMS, CHUNKS), dim3(512), 0, stream,
                       xhi, xmid, cbhi, cbmid, wsA, wsB, wsTop2);
    hipLaunchKernelGGL(vq_refine_kernel,  dim3(4096), dim3(256), 0, stream,
                       x, cb, wsA, wsB, wsTop2, wsIdx, out4);
    hipLaunchKernelGGL(vq_gather_kernel,  dim3(4096), dim3(256), 0, stream,
                       x, cb, wsIdx, out0, out3, wsPart);
    hipLaunchKernelGGL(vq_loss_kernel,    dim3(1),   dim3(256), 0, stream,
                       wsPart, out1, out2);
}